// Round 1
// baseline (99.012 us; speedup 1.0000x reference)
//
#include <hip/hip_runtime.h>
#include <math.h>

#define N_EDGES   1000000
#define N_NODES   100000
#define THR_LO    0.6f
#define THR_HI    0.8f
#define LOG_CLAMP -100.0f

#define NBLOCKS   2048
#define BLOCK     256

// d_ws layout:
//   0x00000: float4 part[NBLOCKS]      32 KB  (block partials; written unconditionally)

__device__ __forceinline__ float sq4(float4 a, float4 b) {
    float dx = a.x - b.x;
    float dy = a.y - b.y;
    float dz = a.z - b.z;
    float dw = a.w - b.w;
    return dx * dx + dy * dy + dz * dz + dw * dw;
}

__device__ __forceinline__ void accum_edge(float s, int simflag,
                                           float& sim, float& dis) {
    float d = sqrtf(s);
    if (simflag) {
        sim += fminf(d, 100.0f);                  // -max(log(exp(-d)),-100)
    } else {
        float p = expf(-d);
        dis += -fmaxf(log1pf(-p), LOG_CLAMP);
    }
}

// ---------------- fused main: inline classify + compact + fp32 gathers ----------------
__global__ void __launch_bounds__(BLOCK)
edge_loss_kernel(const int2* __restrict__ edges,
                 const float* __restrict__ probas,
                 const float4* __restrict__ feats,   // N_NODES rows of 16 float4 (256 B)
                 float4* __restrict__ part) {
    const int lane = threadIdx.x & 63;
    const int wave = threadIdx.x >> 6;
    const int grp  = lane >> 2;                    // 16 groups of 4 lanes
    const int sub  = lane & 3;

    __shared__ int sh_i[4][64];
    __shared__ int sh_j[4][64];

    float sim = 0.f, dis = 0.f, ns = 0.f, nd = 0.f;

    const int gstride = gridDim.x * blockDim.x;
    for (int base = blockIdx.x * blockDim.x; base < N_EDGES; base += gstride) {
        // ---- mask phase: 1 edge per lane, classify straight from probas (L2-resident)
        int e = base + threadIdx.x;
        bool in = (e < N_EDGES);
        int2 ij = in ? edges[e] : make_int2(0, 0);
        float pi = probas[ij.x];
        float pj = probas[ij.y];
        bool hi_i = pi >= THR_HI, hi_j = pj >= THR_HI;
        bool lo_i = pi <  THR_LO, lo_j = pj <  THR_LO;
        bool msim = in && hi_i && hi_j;
        bool mdis = in && ((hi_i && lo_j) || (hi_j && lo_i));

        unsigned long long balsim = __ballot(msim);
        unsigned long long baldis = __ballot(mdis);
        unsigned long long m      = balsim | baldis;
        if (lane == 0) {
            ns += (float)__popcll(balsim);
            nd += (float)__popcll(baldis);
        }
        int count = __popcll(m);

        if (msim | mdis) {
            int prefix = __popcll(m & ((1ULL << lane) - 1ULL));
            sh_i[wave][prefix] = ij.x | (msim ? (int)0x80000000 : 0);
            sh_j[wave][prefix] = ij.y;
        }
        __syncthreads();

        // ---- cooperative phase: 4 lanes/edge, fp32 rows (256 B), 8 loads in flight
        for (int t = grp; t < count; t += 16) {
            int xi = sh_i[wave][t];
            int xj = sh_j[wave][t];

            const float4* ri = feats + (size_t)(xi & 0x7FFFFFFF) * 16;
            const float4* rj = feats + (size_t)xj * 16;

            // each lane covers 16 of the 64 dims: 4 float4 per row, 2 rows
            float4 a0 = ri[sub];
            float4 a1 = ri[sub + 4];
            float4 a2 = ri[sub + 8];
            float4 a3 = ri[sub + 12];
            float4 b0 = rj[sub];
            float4 b1 = rj[sub + 4];
            float4 b2 = rj[sub + 8];
            float4 b3 = rj[sub + 12];

            float s = sq4(a0, b0) + sq4(a1, b1) + sq4(a2, b2) + sq4(a3, b3);

            s += __shfl_xor(s, 1);
            s += __shfl_xor(s, 2);

            if (sub == 0) {
                accum_edge(s, ((unsigned)xi) >> 31, sim, dis);
            }
        }
        __syncthreads();
    }

    // ---- block reduction (plain store, no global atomics) ----
    #pragma unroll
    for (int off = 32; off > 0; off >>= 1) {
        sim += __shfl_down(sim, off);
        dis += __shfl_down(dis, off);
        ns  += __shfl_down(ns,  off);
        nd  += __shfl_down(nd,  off);
    }
    __shared__ float lds[4][4];
    if (lane == 0) {
        lds[wave][0] = sim; lds[wave][1] = dis;
        lds[wave][2] = ns;  lds[wave][3] = nd;
    }
    __syncthreads();
    if (threadIdx.x == 0) {
        float a = 0.f, b = 0.f, c = 0.f, d4 = 0.f;
        #pragma unroll
        for (int w = 0; w < 4; ++w) {
            a += lds[w][0]; b += lds[w][1]; c += lds[w][2]; d4 += lds[w][3];
        }
        part[blockIdx.x] = make_float4(a, b, c, d4);
    }
}

__global__ void __launch_bounds__(BLOCK)
finalize_kernel(const float4* __restrict__ part,
                float* __restrict__ out) {
    float a = 0.f, b = 0.f, c = 0.f, d4 = 0.f;
    for (int i = threadIdx.x; i < NBLOCKS; i += BLOCK) {
        float4 p = part[i];
        a += p.x; b += p.y; c += p.z; d4 += p.w;
    }
    #pragma unroll
    for (int off = 32; off > 0; off >>= 1) {
        a  += __shfl_down(a,  off);
        b  += __shfl_down(b,  off);
        c  += __shfl_down(c,  off);
        d4 += __shfl_down(d4, off);
    }
    __shared__ float lds[4][4];
    int lane = threadIdx.x & 63;
    int wave = threadIdx.x >> 6;
    if (lane == 0) {
        lds[wave][0] = a; lds[wave][1] = b; lds[wave][2] = c; lds[wave][3] = d4;
    }
    __syncthreads();
    if (threadIdx.x == 0) {
        float sim_sum = 0.f, disim_sum = 0.f, n_sim = 0.f, n_disim = 0.f;
        #pragma unroll
        for (int w = 0; w < 4; ++w) {
            sim_sum   += lds[w][0];
            disim_sum += lds[w][1];
            n_sim     += lds[w][2];
            n_disim   += lds[w][3];
        }
        float total = n_sim + n_disim;
        out[0] = (sim_sum * (n_disim / total) +
                  disim_sum * (n_sim / total)) / total;
    }
}

extern "C" void kernel_launch(void* const* d_in, const int* in_sizes, int n_in,
                              void* d_out, int out_size, void* d_ws, size_t ws_size,
                              hipStream_t stream) {
    const int*   edges  = (const int*)d_in[0];    // (N_EDGES, 2) int32
    const float* probas = (const float*)d_in[1];  // (N_NODES,)
    const float* feats  = (const float*)d_in[2];  // (N_NODES, 64) fp32

    float4* part = (float4*)d_ws;

    edge_loss_kernel<<<NBLOCKS, BLOCK, 0, stream>>>(
        (const int2*)edges, probas, (const float4*)feats, part);

    finalize_kernel<<<1, BLOCK, 0, stream>>>(part, (float*)d_out);
}